// Round 1
// baseline (531.071 us; speedup 1.0000x reference)
//
#include <hip/hip_runtime.h>

#define D_ORIENT 12
#define HW 16384                 // 128*128 floats per orientation slice
#define NT 256                   // threads per block, both kernels

// ---------------------------------------------------------------------------
// Kernel 1: one block per (b, c, d) orientation slice. Pure max-reduce of the
// 16384-float slice (no index tracking needed: the flat argmax is only used
// as idx // HW, i.e. the winning orientation, which equals the smallest d
// whose slice max equals the global max over the 12 slices).
// 16384/4 float4 / 256 threads = 16 fully-coalesced iterations per thread.
// ---------------------------------------------------------------------------
__global__ __launch_bounds__(NT) void slice_max_kernel(const float* __restrict__ x,
                                                       float* __restrict__ smax) {
    const int s = blockIdx.x;    // slice id in [0, B*C*12)
    const float4* __restrict__ src4 = (const float4*)(x + (size_t)s * HW);
    const int tid = threadIdx.x;

    float best = -__builtin_inff();
    #pragma unroll
    for (int i = 0; i < HW / 4 / NT; ++i) {          // 16 iters
        float4 v = src4[tid + i * NT];
        // 3-deep fmax tree per float4 (fusable to v_max3_f32), no serial
        // cmp/cndmask chain through an index register.
        float m01 = fmaxf(v.x, v.y);
        float m23 = fmaxf(v.z, v.w);
        best = fmaxf(best, fmaxf(m01, m23));
    }

    // wave-64 shuffle max reduction
    #pragma unroll
    for (int off = 32; off >= 1; off >>= 1)
        best = fmaxf(best, __shfl_down(best, off, 64));

    __shared__ float s_w[NT / 64];
    const int wave = tid >> 6;
    const int lane = tid & 63;
    if (lane == 0) s_w[wave] = best;
    __syncthreads();
    if (tid == 0) {
        float m = fmaxf(fmaxf(s_w[0], s_w[1]), fmaxf(s_w[2], s_w[3]));
        smax[s] = m;
    }
}

// ---------------------------------------------------------------------------
// Kernel 2: one block per (b, c). Pick the smallest d whose slice max equals
// the global max (first-occurrence tie-break, matching jnp.argmax on the
// flattened (12,H,W) axis), then copy that HxW slice to the output.
// ---------------------------------------------------------------------------
__global__ __launch_bounds__(NT) void gather_kernel(const float* __restrict__ x,
                                                    const float* __restrict__ smax,
                                                    float* __restrict__ out) {
    const int bc = blockIdx.x;
    __shared__ int s_d;
    if (threadIdx.x == 0) {
        const float* __restrict__ m = smax + bc * D_ORIENT;
        float g = m[0];
        int d = 0;
        #pragma unroll
        for (int k = 1; k < D_ORIENT; ++k) {
            float v = m[k];
            if (v > g) { g = v; d = k; }   // strict '>' keeps smallest d on ties
        }
        s_d = d;
    }
    __syncthreads();

    const float4* __restrict__ win =
        (const float4*)(x + ((size_t)bc * D_ORIENT + (size_t)s_d) * HW);
    float4* __restrict__ dst = (float4*)(out + (size_t)bc * HW);
    const int tid = threadIdx.x;
    #pragma unroll
    for (int i = 0; i < HW / 4 / NT; ++i)            // 16 iters
        dst[tid + i * NT] = win[tid + i * NT];
}

extern "C" void kernel_launch(void* const* d_in, const int* in_sizes, int n_in,
                              void* d_out, int out_size, void* d_ws, size_t ws_size,
                              hipStream_t stream) {
    const float* x = (const float*)d_in[0];
    float* out = (float*)d_out;
    float* smax = (float*)d_ws;              // needs B*C*12 floats = 24 KB
    const int n_bc = out_size / HW;          // B*C = 512 (same convention as prior kernel)

    slice_max_kernel<<<n_bc * D_ORIENT, NT, 0, stream>>>(x, smax);
    gather_kernel<<<n_bc, NT, 0, stream>>>(x, smax, out);
}

// Round 2
// 526.596 us; speedup vs baseline: 1.0085x; 1.0085x over previous
//
#include <hip/hip_runtime.h>

#define D_ORIENT 12
#define HW 16384                    // 128*128
#define SLICE (D_ORIENT * HW)       // 196608 elements per (b,c)
#define NTHREADS 1024

// One block per (b,c). Single fused kernel (one launch, gather reuses any
// L2/L3 residency from the scan).
//
// Phase 1: per-slice max scan. Key observation: jnp.argmax's flat index is
// only consumed as idx // HW, i.e. the winning orientation d = the smallest
// d whose slice max equals the global max. Each thread's strided float4 walk
// visits the 12 slices IN ORDER (4 iterations of 1024 float4 per slice), so
// we compute a pure fmax-tree slice max (no index tracking in the inner
// loop, fusable to v_max3_f32) and do a single (val, d) compare per slice.
// Strict '>' keeps the smallest d per thread; the cross-lane reduction uses
// (v > best) || (v == best && d < bestd) to keep first-occurrence semantics.
//
// Phase 2: cooperative float4 copy of the winning HxW slice.
__global__ __launch_bounds__(NTHREADS) void opool_kernel(const float* __restrict__ x,
                                                         float* __restrict__ out) {
    const int bc = blockIdx.x;
    const float* __restrict__ src = x + (size_t)bc * SLICE;
    const int tid = threadIdx.x;

    float best = -__builtin_inff();
    int bestd = 0;

    const float4* __restrict__ src4 = (const float4*)src;
    #pragma unroll
    for (int d = 0; d < D_ORIENT; ++d) {
        float m = -__builtin_inff();
        #pragma unroll
        for (int j = 0; j < HW / 4 / NTHREADS; ++j) {        // 4 iters/slice
            float4 v = src4[d * (HW / 4) + j * NTHREADS + tid];
            float m01 = fmaxf(v.x, v.y);
            float m23 = fmaxf(v.z, v.w);
            m = fmaxf(m, fmaxf(m01, m23));
        }
        if (m > best) { best = m; bestd = d; }               // 1 cmp per slice
    }

    // wave-64 shuffle reduction, min-d tie-break
    #pragma unroll
    for (int off = 32; off >= 1; off >>= 1) {
        float ov = __shfl_down(best, off, 64);
        int   od = __shfl_down(bestd, off, 64);
        if (ov > best || (ov == best && od < bestd)) { best = ov; bestd = od; }
    }

    __shared__ float s_val[NTHREADS / 64];
    __shared__ int   s_dw[NTHREADS / 64];
    __shared__ int   s_d;
    const int wave = tid >> 6;
    const int lane = tid & 63;
    if (lane == 0) { s_val[wave] = best; s_dw[wave] = bestd; }
    __syncthreads();
    if (tid == 0) {
        float bv = s_val[0];
        int   bd = s_dw[0];
        #pragma unroll
        for (int w = 1; w < NTHREADS / 64; ++w) {
            float v = s_val[w];
            int   d2 = s_dw[w];
            if (v > bv || (v == bv && d2 < bd)) { bv = v; bd = d2; }
        }
        s_d = bd;
    }
    __syncthreads();

    // Phase 2: copy winning slice (16384 floats = 4096 float4 / 1024 thr = 4 iters)
    const float4* __restrict__ win = (const float4*)(src + (size_t)s_d * HW);
    float4* __restrict__ dst = (float4*)(out + (size_t)bc * HW);
    #pragma unroll
    for (int i = tid; i < HW / 4; i += NTHREADS) {
        dst[i] = win[i];
    }
}

extern "C" void kernel_launch(void* const* d_in, const int* in_sizes, int n_in,
                              void* d_out, int out_size, void* d_ws, size_t ws_size,
                              hipStream_t stream) {
    const float* x = (const float*)d_in[0];
    float* out = (float*)d_out;
    const int n_bc = out_size / HW;   // B*C = 512
    opool_kernel<<<n_bc, NTHREADS, 0, stream>>>(x, out);
}